// Round 19
// baseline (20.709 us; speedup 1.0000x reference)
//
#include <hip/hip_runtime.h>

// Problem constants
#define NB 64
#define NL 128
#define NQ 128
#define NE 16384

// ws float layout
#define WS_TW    0          // total weight (written by prep oct-0 block)
#define WS_PART  8          // 256 per-block numerator partials (ends 264)
// ws ushort layout, offsets in ushorts from ws base
#define US_WB    544                     // [i][j] W bf16 (byte 1088, 16B aligned)
#define US_ATB   (US_WB + 16384)         // [q][p] A^T bf16

using short8 = __attribute__((ext_vector_type(8))) short;  // 8 bf16
using f32x4  = __attribute__((ext_vector_type(4))) float;

// fp32 -> bf16 bits, round-to-nearest-even
__device__ inline unsigned short f2bf(float f) {
    const unsigned u = __float_as_uint(f);
    return (unsigned short)((u + 0x7fffu + ((u >> 16) & 1u)) >> 16);
}

// ---------------------------------------------------------------------------
// prep: 16 blocks x 512 threads (R18-identical).
//  blk 0-7 : oct = blk. W rows [oct*16,+16): 2-packed scan of all edges,
//            filtered LDS scatter [16][132] fp32, emit bf16 -> WB.
//            oct 0 also reduces/writes total weight.
//  blk 8-15: ATB[q][p] = bf16 A_fid[p][q] (coalesced reads, 2B transposed
//            stores), 2048 elems per block.
// ---------------------------------------------------------------------------
__global__ __launch_bounds__(512) void prep_kernel(const float* __restrict__ dhw,
                                                   const float* __restrict__ derr,
                                                   const int*  __restrict__ pairs,
                                                   const float* __restrict__ wts,
                                                   float* __restrict__ ws) {
    const int t = threadIdx.x, blk = blockIdx.x;
    unsigned short* us = (unsigned short*)ws;

    if (blk < 8) {
        __shared__ float Wl[16 * 132];
        __shared__ float red[8];
        const int oct = blk;                           // i-rows [oct*16,+16)
        for (int idx = t; idx < 16 * 132; idx += 512) Wl[idx] = 0.f;
        __syncthreads();

        float tw = 0.f;
        #pragma unroll 4
        for (int r = 0; r < 16; ++r) {
            const int e2 = t + 512 * r;                // 2-edge pack, [0,8192)
            const int4   pr = ((const int4*)pairs)[e2];
            const float2 w2 = ((const float2*)wts)[e2];
            tw += w2.x + w2.y;
            if ((pr.x >> 4) == oct)
                atomicAdd(&Wl[(pr.x & 15) * 132 + pr.y], w2.x);
            if ((pr.z >> 4) == oct)
                atomicAdd(&Wl[(pr.z & 15) * 132 + pr.w], w2.y);
        }
        __syncthreads();

        // emit bf16 W rows (f2bf applied ONCE here; main loads short8 direct)
        #pragma unroll
        for (int r = 0; r < 4; ++r) {
            const int idx = t + 512 * r;               // [0, 2048)
            const int row = idx >> 7, col = idx & 127;
            us[US_WB + oct * 2048 + idx] = f2bf(Wl[row * 132 + col]);
        }

        if (oct == 0) {
            #pragma unroll
            for (int off = 32; off; off >>= 1) tw += __shfl_down(tw, off, 64);
            if ((t & 63) == 0) red[t >> 6] = tw;
            __syncthreads();
            if (t == 0) {
                float s = 0.f;
                #pragma unroll
                for (int k = 0; k < 8; ++k) s += red[k];
                ws[WS_TW] = s;
            }
        }
    } else {
        #pragma unroll
        for (int r = 0; r < 4; ++r) {
            const int idx = (blk - 8) * 2048 + t + 512 * r;    // [0, 16384)
            const float hw = dhw[idx], er = derr[idx];
            const float a  = (hw == 1.0f) ? fmaxf(1.0f - er, 0.f) : 0.f;
            const int p = idx >> 7, q = idx & 127;
            us[US_ATB + q * 128 + p] = f2bf(a);
        }
    }
}

// ---------------------------------------------------------------------------
// main: 256 blocks x 512 threads (R18 body; gb gather rotated per lane-group
// to break the 8-way bank conflict: group g reads element (d+g)&7 at step d,
// so within each instruction row&7 varies across groups -> banks spread).
// block = (b = blk>>2, qtr = blk&3 -> i-rows [qtr*32, qtr*32+32)).
// ---------------------------------------------------------------------------
__global__ __launch_bounds__(512) void main_kernel(const float* __restrict__ P,
                                                   float* __restrict__ ws) {
    __shared__ unsigned short Pbl[128 * 136];  // 34816 B bf16 P_b (padded)
    __shared__ float redS[8];

    const int t   = threadIdx.x;
    const int blk = blockIdx.x;                // [0,256)
    const int b   = blk >> 2;
    const int qtr = blk & 3;                   // i-rows [qtr*32, qtr*32+32)
    const float* __restrict__ Pb = P + b * 16384;
    const unsigned short* us = (const unsigned short*)ws;
    const unsigned short* __restrict__ ATB = us + US_ATB;
    const unsigned short* __restrict__ WB  = us + US_WB;

    // 1. load P_b (coalesced) -> LDS bf16, padded stride 136
    float4 pv[8];
    #pragma unroll
    for (int r = 0; r < 8; ++r) pv[r] = ((const float4*)Pb)[t + 512 * r];
    #pragma unroll
    for (int r = 0; r < 8; ++r) {
        const int f   = t + 512 * r;           // ushort4 unit within [128][128]
        const int row = f >> 5, c4 = (f & 31) * 4;
        ushort4 u;
        u.x = f2bf(pv[r].x); u.y = f2bf(pv[r].y);
        u.z = f2bf(pv[r].z); u.w = f2bf(pv[r].w);
        *(ushort4*)&Pbl[row * 136 + c4] = u;
    }
    __syncthreads();

    const int wv   = t >> 6;                   // wave -> q-tile
    const int lane = t & 63;
    const int l15  = lane & 15;
    const int g    = lane >> 4;                // 16-lane group 0..3
    const int kb   = g * 8;
    const int ncol = wv * 16 + l15;

    // 2. B-operand fragments (gb: group-rotated gather order, conflict-spread)
    short8 gb8[4], yb8[4];
    #pragma unroll
    for (int kk = 0; kk < 4; ++kk) {
        const int k0 = kk * 32 + kb;
        short8 gfrag;
        #pragma unroll
        for (int d = 0; d < 8; ++d) {
            const int dd = (d + g) & 7;        // rotate start by lane group
            gfrag[dd] = (short)Pbl[(k0 + dd) * 136 + ncol];    // P_b[j][ncol]
        }
        gb8[kk] = gfrag;
        yb8[kk] = *(const short8*)&ATB[ncol * 128 + k0];       // L2-hot
    }

    // 3. two i-tiles
    float s = 0.f;
    #pragma unroll
    for (int uu = 0; uu < 2; ++uu) {
        const int mrow = qtr * 32 + uu * 16 + l15;             // global i row
        f32x4 accG = {0.f, 0.f, 0.f, 0.f};
        f32x4 accY = {0.f, 0.f, 0.f, 0.f};
        #pragma unroll
        for (int kk = 0; kk < 4; ++kk) {
            const int k0 = kk * 32 + kb;
            const short8 wa = *(const short8*)&WB[mrow * 128 + k0];  // L2-hot
            const short8 pa = *(const short8*)&Pbl[mrow * 136 + k0];
            accG = __builtin_amdgcn_mfma_f32_16x16x32_bf16(wa, gb8[kk], accG, 0, 0, 0);
            accY = __builtin_amdgcn_mfma_f32_16x16x32_bf16(pa, yb8[kk], accY, 0, 0, 0);
        }
        s += accG[0] * accY[0] + accG[1] * accY[1]
           + accG[2] * accY[2] + accG[3] * accY[3];
    }

    // 4. block reduce; one plain store per block
    #pragma unroll
    for (int off = 32; off; off >>= 1) s += __shfl_down(s, off, 64);
    if (lane == 0) redS[wv] = s;
    __syncthreads();
    if (t == 0) {
        float ss = 0.f;
        #pragma unroll
        for (int k = 0; k < 8; ++k) ss += redS[k];
        ws[WS_PART + blk] = ss;                // distinct slot, no atomics
    }
}

// ---------------------------------------------------------------------------
// finalize: 1 block x 256 threads; loss = -(sum(part)/B)/max(tw,1e-8)
// ---------------------------------------------------------------------------
__global__ __launch_bounds__(256) void finalize_kernel(const float* __restrict__ ws,
                                                       float* __restrict__ out) {
    const int t = threadIdx.x, lane = t & 63, wv = t >> 6;
    float n = ws[WS_PART + t];
    #pragma unroll
    for (int off = 32; off; off >>= 1) n += __shfl_down(n, off, 64);
    __shared__ float red[4];
    if (lane == 0) red[wv] = n;
    __syncthreads();
    if (t == 0) {
        const float num = red[0] + red[1] + red[2] + red[3];
        out[0] = -num / ((float)NB * fmaxf(ws[WS_TW], 1e-8f));
    }
}

extern "C" void kernel_launch(void* const* d_in, const int* in_sizes, int n_in,
                              void* d_out, int out_size, void* d_ws, size_t ws_size,
                              hipStream_t stream) {
    const float* P    = (const float*)d_in[0];
    const float* dhw  = (const float*)d_in[1];
    const float* derr = (const float*)d_in[2];
    const int*   prs  = (const int*)d_in[3];
    const float* wts  = (const float*)d_in[4];
    float* ws  = (float*)d_ws;
    float* out = (float*)d_out;

    prep_kernel<<<16, 512, 0, stream>>>(dhw, derr, prs, wts, ws);
    main_kernel<<<256, 512, 0, stream>>>(P, ws);
    finalize_kernel<<<1, 256, 0, stream>>>(ws, out);
}

// Round 20
// 19.403 us; speedup vs baseline: 1.0673x; 1.0673x over previous
//
#include <hip/hip_runtime.h>

// Problem constants
#define NB 64
#define NL 128
#define NQ 128
#define NE 16384

// ws float layout
#define WS_TW    0          // total weight (written by prep oct-0 block)
#define WS_PART  8          // 256 per-block numerator partials (ends 264)
// ws ushort layout, offsets in ushorts from ws base
#define US_WB    544                     // [i][j] W bf16 (byte 1088, 16B aligned)
#define US_ATB   (US_WB + 16384)         // [q][p] A^T bf16

using short8 = __attribute__((ext_vector_type(8))) short;  // 8 bf16
using f32x4  = __attribute__((ext_vector_type(4))) float;

// fp32 -> bf16 bits, round-to-nearest-even
__device__ inline unsigned short f2bf(float f) {
    const unsigned u = __float_as_uint(f);
    return (unsigned short)((u + 0x7fffu + ((u >> 16) & 1u)) >> 16);
}

// ---------------------------------------------------------------------------
// prep: 16 blocks x 512 threads.
//  blk 0-7 : oct = blk. W rows [oct*16,+16): 2-packed scan of all edges,
//            filtered LDS scatter [16][132] fp32, emit bf16 -> WB.
//            oct 0 also reduces/writes total weight.
//  blk 8-15: ATB[q][p] = bf16 A_fid[p][q] (coalesced reads, 2B transposed
//            stores), 2048 elems per block.
// ---------------------------------------------------------------------------
__global__ __launch_bounds__(512) void prep_kernel(const float* __restrict__ dhw,
                                                   const float* __restrict__ derr,
                                                   const int*  __restrict__ pairs,
                                                   const float* __restrict__ wts,
                                                   float* __restrict__ ws) {
    const int t = threadIdx.x, blk = blockIdx.x;
    unsigned short* us = (unsigned short*)ws;

    if (blk < 8) {
        __shared__ float Wl[16 * 132];
        __shared__ float red[8];
        const int oct = blk;                           // i-rows [oct*16,+16)
        for (int idx = t; idx < 16 * 132; idx += 512) Wl[idx] = 0.f;
        __syncthreads();

        float tw = 0.f;
        #pragma unroll 4
        for (int r = 0; r < 16; ++r) {
            const int e2 = t + 512 * r;                // 2-edge pack, [0,8192)
            const int4   pr = ((const int4*)pairs)[e2];
            const float2 w2 = ((const float2*)wts)[e2];
            tw += w2.x + w2.y;
            if ((pr.x >> 4) == oct)
                atomicAdd(&Wl[(pr.x & 15) * 132 + pr.y], w2.x);
            if ((pr.z >> 4) == oct)
                atomicAdd(&Wl[(pr.z & 15) * 132 + pr.w], w2.y);
        }
        __syncthreads();

        // emit bf16 W rows (f2bf applied ONCE here; main loads short8 direct)
        #pragma unroll
        for (int r = 0; r < 4; ++r) {
            const int idx = t + 512 * r;               // [0, 2048)
            const int row = idx >> 7, col = idx & 127;
            us[US_WB + oct * 2048 + idx] = f2bf(Wl[row * 132 + col]);
        }

        if (oct == 0) {
            #pragma unroll
            for (int off = 32; off; off >>= 1) tw += __shfl_down(tw, off, 64);
            if ((t & 63) == 0) red[t >> 6] = tw;
            __syncthreads();
            if (t == 0) {
                float s = 0.f;
                #pragma unroll
                for (int k = 0; k < 8; ++k) s += red[k];
                ws[WS_TW] = s;
            }
        }
    } else {
        #pragma unroll
        for (int r = 0; r < 4; ++r) {
            const int idx = (blk - 8) * 2048 + t + 512 * r;    // [0, 16384)
            const float hw = dhw[idx], er = derr[idx];
            const float a  = (hw == 1.0f) ? fmaxf(1.0f - er, 0.f) : 0.f;
            const int p = idx >> 7, q = idx & 127;
            us[US_ATB + q * 128 + p] = f2bf(a);
        }
    }
}

// ---------------------------------------------------------------------------
// main: 256 blocks x 512 threads.
// block = (b = blk>>2, qtr = blk&3 -> i-rows [qtr*32, qtr*32+32)).
//  1. load full P_b -> LDS bf16 [128][136] (pad: conflict-free rows+cols)
//  2. gb frags from P_b LDS columns; yb = contiguous short8 from ATB (L2)
//  3. per i-tile (2): wa = contiguous short8 from WB (L2), pa = P_b LDS rows;
//     accG = W*P_b frag, accY = P_b*A frag; s += <G,Y> (layout-invariant)
//  4. block-reduce s -> WS_PART[blk] (plain store, distinct slot).
// ---------------------------------------------------------------------------
__global__ __launch_bounds__(512) void main_kernel(const float* __restrict__ P,
                                                   float* __restrict__ ws) {
    __shared__ unsigned short Pbl[128 * 136];  // 34816 B bf16 P_b (padded)
    __shared__ float redS[8];

    const int t   = threadIdx.x;
    const int blk = blockIdx.x;                // [0,256)
    const int b   = blk >> 2;
    const int qtr = blk & 3;                   // i-rows [qtr*32, qtr*32+32)
    const float* __restrict__ Pb = P + b * 16384;
    const unsigned short* us = (const unsigned short*)ws;
    const unsigned short* __restrict__ ATB = us + US_ATB;
    const unsigned short* __restrict__ WB  = us + US_WB;

    // 1. load P_b (coalesced) -> LDS bf16, padded stride 136
    float4 pv[8];
    #pragma unroll
    for (int r = 0; r < 8; ++r) pv[r] = ((const float4*)Pb)[t + 512 * r];
    #pragma unroll
    for (int r = 0; r < 8; ++r) {
        const int f   = t + 512 * r;           // ushort4 unit within [128][128]
        const int row = f >> 5, c4 = (f & 31) * 4;
        ushort4 u;
        u.x = f2bf(pv[r].x); u.y = f2bf(pv[r].y);
        u.z = f2bf(pv[r].z); u.w = f2bf(pv[r].w);
        *(ushort4*)&Pbl[row * 136 + c4] = u;
    }
    __syncthreads();

    const int wv   = t >> 6;                   // wave -> q-tile
    const int lane = t & 63;
    const int l15  = lane & 15;
    const int kb   = (lane >> 4) * 8;
    const int ncol = wv * 16 + l15;

    // 2. B-operand fragments
    short8 gb8[4], yb8[4];
    #pragma unroll
    for (int kk = 0; kk < 4; ++kk) {
        const int k0 = kk * 32 + kb;
        short8 g;
        #pragma unroll
        for (int d = 0; d < 8; ++d)
            g[d] = (short)Pbl[(k0 + d) * 136 + ncol];          // P_b[j][ncol]
        gb8[kk] = g;
        yb8[kk] = *(const short8*)&ATB[ncol * 128 + k0];       // L2-hot
    }

    // 3. two i-tiles
    float s = 0.f;
    #pragma unroll
    for (int uu = 0; uu < 2; ++uu) {
        const int mrow = qtr * 32 + uu * 16 + l15;             // global i row
        f32x4 accG = {0.f, 0.f, 0.f, 0.f};
        f32x4 accY = {0.f, 0.f, 0.f, 0.f};
        #pragma unroll
        for (int kk = 0; kk < 4; ++kk) {
            const int k0 = kk * 32 + kb;
            const short8 wa = *(const short8*)&WB[mrow * 128 + k0];  // L2-hot
            const short8 pa = *(const short8*)&Pbl[mrow * 136 + k0];
            accG = __builtin_amdgcn_mfma_f32_16x16x32_bf16(wa, gb8[kk], accG, 0, 0, 0);
            accY = __builtin_amdgcn_mfma_f32_16x16x32_bf16(pa, yb8[kk], accY, 0, 0, 0);
        }
        s += accG[0] * accY[0] + accG[1] * accY[1]
           + accG[2] * accY[2] + accG[3] * accY[3];
    }

    // 4. block reduce; one plain store per block
    #pragma unroll
    for (int off = 32; off; off >>= 1) s += __shfl_down(s, off, 64);
    if (lane == 0) redS[wv] = s;
    __syncthreads();
    if (t == 0) {
        float ss = 0.f;
        #pragma unroll
        for (int k = 0; k < 8; ++k) ss += redS[k];
        ws[WS_PART + blk] = ss;                // distinct slot, no atomics
    }
}

// ---------------------------------------------------------------------------
// finalize: 1 block x 256 threads; loss = -(sum(part)/B)/max(tw,1e-8)
// ---------------------------------------------------------------------------
__global__ __launch_bounds__(256) void finalize_kernel(const float* __restrict__ ws,
                                                       float* __restrict__ out) {
    const int t = threadIdx.x, lane = t & 63, wv = t >> 6;
    float n = ws[WS_PART + t];
    #pragma unroll
    for (int off = 32; off; off >>= 1) n += __shfl_down(n, off, 64);
    __shared__ float red[4];
    if (lane == 0) red[wv] = n;
    __syncthreads();
    if (t == 0) {
        const float num = red[0] + red[1] + red[2] + red[3];
        out[0] = -num / ((float)NB * fmaxf(ws[WS_TW], 1e-8f));
    }
}

extern "C" void kernel_launch(void* const* d_in, const int* in_sizes, int n_in,
                              void* d_out, int out_size, void* d_ws, size_t ws_size,
                              hipStream_t stream) {
    const float* P    = (const float*)d_in[0];
    const float* dhw  = (const float*)d_in[1];
    const float* derr = (const float*)d_in[2];
    const int*   prs  = (const int*)d_in[3];
    const float* wts  = (const float*)d_in[4];
    float* ws  = (float*)d_ws;
    float* out = (float*)d_out;

    prep_kernel<<<16, 512, 0, stream>>>(dhw, derr, prs, wts, ws);
    main_kernel<<<256, 512, 0, stream>>>(P, ws);
    finalize_kernel<<<1, 256, 0, stream>>>(ws, out);
}